// Round 8
// baseline (564.980 us; speedup 1.0000x reference)
//
#include <hip/hip_runtime.h>
#include <hip/hip_bf16.h>

typedef short short8 __attribute__((ext_vector_type(8)));
typedef short short4v __attribute__((ext_vector_type(4)));
typedef float f32x4 __attribute__((ext_vector_type(4)));

#define SHIFT_ 32

__device__ __forceinline__ float bf2f(unsigned short u) {
    union { unsigned int i; float f; } z; z.i = ((unsigned)u) << 16; return z.f;
}
__device__ __forceinline__ unsigned short f2bf(float f) {
    union { float f; unsigned int i; } z; z.f = f;
    unsigned int x = z.i;
    x += 0x7fffu + ((x >> 16) & 1u);   // round-to-nearest-even
    return (unsigned short)(x >> 16);
}

// ---------------- fp32 -> bf16 weight conversion (once per launch) --------
__global__ __launch_bounds__(256)
void f2bf_kernel(const float* __restrict__ src, unsigned short* __restrict__ dst) {
    int i = (blockIdx.x * 256 + threadIdx.x) * 4;
    f32x4 v = *(const f32x4*)(src + i);
    short4v o;
#pragma unroll
    for (int j = 0; j < 4; j++) o[j] = (short)f2bf(v[j]);
    *(short4v*)(dst + i) = o;
}

// ---------------- LayerNorm (+roll on source index), fp32 in, bf16 out ----
__global__ __launch_bounds__(256)
void ln_kernel(const float* __restrict__ src,
               const float* __restrict__ gam,
               const float* __restrict__ bet,
               unsigned short* __restrict__ dst, int roll) {
    int wid = threadIdx.x >> 6, lane = threadIdx.x & 63;
    int m = (blockIdx.x << 2) + wid;              // output row in [0, 32768)
    int b = m >> 12, s = m & 4095;
    int ms = (b << 12) | ((s + roll) & 4095);     // source row
    const float* p = src + (size_t)ms * 512 + lane * 8;
    f32x4 v0 = *(const f32x4*)p;
    f32x4 v1 = *(const f32x4*)(p + 4);
    float f[8], sum = 0.f, sq = 0.f;
#pragma unroll
    for (int j = 0; j < 4; j++) { f[j] = v0[j]; f[j + 4] = v1[j]; }
#pragma unroll
    for (int j = 0; j < 8; j++) { sum += f[j]; sq += f[j] * f[j]; }
#pragma unroll
    for (int o = 1; o < 64; o <<= 1) { sum += __shfl_xor(sum, o); sq += __shfl_xor(sq, o); }
    float mean = sum * (1.f / 512.f);
    float rstd = rsqrtf(sq * (1.f / 512.f) - mean * mean + 1e-5f);
    const float* gp = gam + lane * 8;
    const float* bp = bet + lane * 8;
    f32x4 g0 = *(const f32x4*)gp, g1 = *(const f32x4*)(gp + 4);
    f32x4 b0 = *(const f32x4*)bp, b1 = *(const f32x4*)(bp + 4);
    short8 ov;
#pragma unroll
    for (int j = 0; j < 4; j++) {
        ov[j]     = (short)f2bf((f[j] - mean) * rstd * g0[j] + b0[j]);
        ov[j + 4] = (short)f2bf((f[j + 4] - mean) * rstd * g1[j] + b1[j]);
    }
    *(short8*)(dst + (size_t)m * 512 + lane * 8) = ov;
}

// ---------------- 256x256-tile MFMA GEMM (BK=64, 8 waves, dbuf LDS) -------
// out = A(M x K) @ Wt(N x K)^T + bias
// EPI: 0 = none, 1 = exact GELU, 2 = +roll(+32) residual (extraf = x fp32),
//      3 = +residual (extraf = x1 fp32)
// OUTF32: write float (d_out) vs bf16 (internal ws tensors)
template <int N, int K, int EPI, bool OUTF32>
__global__ __launch_bounds__(512, 2)
void gemm_kernel(const unsigned short* __restrict__ A,
                 const unsigned short* __restrict__ Wt,
                 const float* __restrict__ bias,
                 void* __restrict__ outv,
                 const float* __restrict__ extraf, int nwg) {
    // 128 KiB: per buf b: A at b*32768 (256x64), B at b*32768+16384 (256x64)
    __shared__ __attribute__((aligned(16))) unsigned short smem[65536];
    // T1: XCD-aware swizzle (grids are multiples of 8; bijective)
    int cpx = nwg >> 3;
    int bid = (blockIdx.x & 7) * cpx + (blockIdx.x >> 3);
    const int nbx = N / 256;
    int bcol = bid % nbx, brow = bid / nbx;
    int m0 = brow << 8, n0 = bcol << 8;
    int t = threadIdx.x, lane = t & 63;
    int w = t >> 6;                 // wave 0..7
    int wrm = w >> 2;               // wave row block: 0/1 (128 rows each)
    int wcn = w & 3;                // wave col block: 0..3 (64 cols each)
    int rsel = lane & 15, ksel = (lane >> 4) << 3;

    // staging chunk geometry: tile = 256 rows x 64 cols bf16 = 2048 x 16B
    // chunk c = i*512 + t : row = c>>3, coff = (c&7)*8 ; LDS offset = c*8
    int srow[4], scoff[4];
#pragma unroll
    for (int i = 0; i < 4; i++) {
        int c = i * 512 + t;
        srow[i] = c >> 3; scoff[i] = (c & 7) << 3;
    }

#define BUFA(b) (smem + (b) * 32768)
#define BUFB(b) (smem + (b) * 32768 + 16384)
#define STAGE(buf, k0)                                                                     \
    do {                                                                                   \
        _Pragma("unroll")                                                                  \
        for (int i = 0; i < 4; i++) {                                                      \
            int c = i * 512 + t;                                                           \
            __builtin_amdgcn_global_load_lds(                                              \
                (const __attribute__((address_space(1))) void*)(A + (size_t)(m0 + srow[i]) * K + (k0) + scoff[i]), \
                (__attribute__((address_space(3))) void*)(BUFA(buf) + c * 8), 16, 0, 0);   \
            __builtin_amdgcn_global_load_lds(                                              \
                (const __attribute__((address_space(1))) void*)(Wt + (size_t)(n0 + srow[i]) * K + (k0) + scoff[i]), \
                (__attribute__((address_space(3))) void*)(BUFB(buf) + c * 8), 16, 0, 0);   \
        }                                                                                  \
    } while (0)

    f32x4 zero4 = {0.f, 0.f, 0.f, 0.f};
    f32x4 acc[8][4];
#pragma unroll
    for (int mi = 0; mi < 8; mi++)
#pragma unroll
        for (int ni = 0; ni < 4; ni++) acc[mi][ni] = zero4;

    STAGE(0, 0);
    __syncthreads();           // vmcnt drains: buf 0 ready
    int cur = 0;
    const int NT = K / 64;
    for (int tt = 0; tt < NT; tt++) {
        if (tt + 1 < NT) STAGE(cur ^ 1, (tt + 1) * 64);   // prefetch next K-tile
#pragma unroll
        for (int kk = 0; kk < 2; kk++) {
            short8 af[8], bf[4];
#pragma unroll
            for (int mi = 0; mi < 8; mi++)
                af[mi] = *(const short8*)(BUFA(cur) + (wrm * 128 + mi * 16 + rsel) * 64 + kk * 32 + ksel);
#pragma unroll
            for (int ni = 0; ni < 4; ni++)
                bf[ni] = *(const short8*)(BUFB(cur) + (wcn * 64 + ni * 16 + rsel) * 64 + kk * 32 + ksel);
#pragma unroll
            for (int mi = 0; mi < 8; mi++)
#pragma unroll
                for (int ni = 0; ni < 4; ni++)
                    acc[mi][ni] = __builtin_amdgcn_mfma_f32_16x16x32_bf16(af[mi], bf[ni], acc[mi][ni], 0, 0, 0);
        }
        __syncthreads();       // drains vmcnt: prefetched buf ready; cur reusable
        cur ^= 1;
    }
#undef STAGE
#undef BUFA
#undef BUFB

    // ---- epilogue: bias (+GELU) in regs, per-wave private LDS staging ----
    // C/D layout col = lane&15, row = (lane>>4)*4 + j  [m89/m91]
    int jbase = (lane >> 4) << 2;
#pragma unroll
    for (int ni = 0; ni < 4; ni++) {
        float bv = bias[n0 + wcn * 64 + ni * 16 + rsel];
#pragma unroll
        for (int mi = 0; mi < 8; mi++)
#pragma unroll
            for (int j = 0; j < 4; j++) {
                float v = acc[mi][ni][j] + bv;
                if (EPI == 1) v = 0.5f * v * (1.f + erff(v * 0.70710678118654752f));
                acc[mi][ni][j] = v;
            }
    }

    if (!OUTF32) {
        unsigned short* eb = smem + w * 8192;      // 16 KB/wave: 128 x 64 bf16
#pragma unroll
        for (int mi = 0; mi < 8; mi++)
#pragma unroll
            for (int ni = 0; ni < 4; ni++)
#pragma unroll
                for (int j = 0; j < 4; j++)
                    eb[(mi * 16 + jbase + j) * 64 + ni * 16 + rsel] = f2bf(acc[mi][ni][j]);
        unsigned short* outp = (unsigned short*)outv;
#pragma unroll
        for (int it = 0; it < 16; it++) {
            int row = it * 8 + (lane >> 3), col = (lane & 7) << 3;
            short8 vv = *(const short8*)(eb + row * 64 + col);
            *(short8*)(outp + (size_t)(m0 + wrm * 128 + row) * N + n0 + wcn * 64 + col) = vv;
        }
    } else {
        float* ebf = (float*)smem + w * 4096;      // 16 KB/wave: 64 x 64 fp32
        float* outp = (float*)outv;
#pragma unroll
        for (int h = 0; h < 2; h++) {
#pragma unroll
            for (int mi = 0; mi < 4; mi++)
#pragma unroll
                for (int ni = 0; ni < 4; ni++)
#pragma unroll
                    for (int j = 0; j < 4; j++)
                        ebf[(mi * 16 + jbase + j) * 64 + ni * 16 + rsel] = acc[h * 4 + mi][ni][j];
#pragma unroll
            for (int it = 0; it < 16; it++) {
                int row = it * 4 + (lane >> 4), c4 = (lane & 15) << 2;
                f32x4 vv = *(const f32x4*)(ebf + row * 64 + c4);
                int grow = m0 + wrm * 128 + h * 64 + row;
                int gcol = n0 + wcn * 64 + c4;
                size_t oidx;
                if (EPI == 2) {
                    int orow = (grow & ~4095) | ((grow + SHIFT_) & 4095);  // roll +32 within batch
                    oidx = (size_t)orow * N + gcol;
                } else {
                    oidx = (size_t)grow * N + gcol;
                }
                if (EPI == 2 || EPI == 3) {
                    f32x4 ex = *(const f32x4*)(extraf + oidx);
                    vv += ex;
                }
                *(f32x4*)(outp + oidx) = vv;
            }
        }
    }
}

// ---------------- MFMA window attention: one wave per (window, head) ------
__global__ __launch_bounds__(256, 2)
void attn_kernel(const unsigned short* __restrict__ qkv,
                 const float* __restrict__ relb,
                 unsigned short* __restrict__ obuf) {
    __shared__ __attribute__((aligned(16))) unsigned short Pl[4][64 * 72];
    __shared__ __attribute__((aligned(16))) unsigned short Vt[4][32 * 72];
    __shared__ float biasd[4][128];
    int wid = threadIdx.x >> 6, lane = threadIdx.x & 63;
    int task = (blockIdx.x << 2) + wid;   // 8192 tasks = 512 windows x 16 heads
    int win = task >> 4, h = task & 15;
    const unsigned short* base = qkv + (size_t)win * 98304 + h * 32;

    float* bd = biasd[wid];
    bd[lane] = relb[lane * 16 + h];
    if (lane < 63) bd[lane + 64] = relb[(lane + 64) * 16 + h];

    int rsel = lane & 15, ksel = (lane >> 4) << 3;
    short8 qf[4], kf[4];
#pragma unroll
    for (int i = 0; i < 4; i++) {
        qf[i] = *(const short8*)(base + (size_t)(i * 16 + rsel) * 1536 + ksel);
        kf[i] = *(const short8*)(base + (size_t)(i * 16 + rsel) * 1536 + 512 + ksel);
    }
    f32x4 zero4 = {0.f, 0.f, 0.f, 0.f};
    f32x4 accS[4][4];
#pragma unroll
    for (int mi = 0; mi < 4; mi++)
#pragma unroll
        for (int ni = 0; ni < 4; ni++) accS[mi][ni] = zero4;
#pragma unroll
    for (int mi = 0; mi < 4; mi++)
#pragma unroll
        for (int ni = 0; ni < 4; ni++)
            accS[mi][ni] = __builtin_amdgcn_mfma_f32_16x16x32_bf16(qf[mi], kf[ni], accS[mi][ni], 0, 0, 0);

    // stage V^T into LDS: vt[d][k] = v[k][d], padded stride 72
    unsigned short* vt = Vt[wid];
#pragma unroll 8
    for (int it = 0; it < 32; it++) {
        int idx = (it << 6) + lane;
        int vr = idx >> 5, vd = idx & 31;
        vt[vd * 72 + vr] = base[(size_t)vr * 1536 + 1024 + vd];
    }
    __syncthreads();

    const float scale = 0.17677669529663687f;  // 1/sqrt(32)
    bool masked = ((win & 63) == 63);
    int jbase = (lane >> 4) << 2;
    float rs[4][4];
#pragma unroll
    for (int mi = 0; mi < 4; mi++) {
#pragma unroll
        for (int ni = 0; ni < 4; ni++) {
            int colb = ni * 16 + rsel;
#pragma unroll
            for (int j = 0; j < 4; j++) {
                int row = mi * 16 + jbase + j;
                float v = accS[mi][ni][j] * scale + bd[row - colb + 63];
                if (masked && ((row < 32) != (colb < 32))) v -= 100.f;
                accS[mi][ni][j] = v;
            }
        }
#pragma unroll
        for (int j = 0; j < 4; j++) {
            float m = fmaxf(fmaxf(accS[mi][0][j], accS[mi][1][j]),
                            fmaxf(accS[mi][2][j], accS[mi][3][j]));
            m = fmaxf(m, __shfl_xor(m, 1));
            m = fmaxf(m, __shfl_xor(m, 2));
            m = fmaxf(m, __shfl_xor(m, 4));
            m = fmaxf(m, __shfl_xor(m, 8));
            float ssum = 0.f;
#pragma unroll
            for (int ni = 0; ni < 4; ni++) {
                float p = __expf(accS[mi][ni][j] - m);
                accS[mi][ni][j] = p; ssum += p;
            }
            ssum += __shfl_xor(ssum, 1);
            ssum += __shfl_xor(ssum, 2);
            ssum += __shfl_xor(ssum, 4);
            ssum += __shfl_xor(ssum, 8);
            rs[mi][j] = 1.f / ssum;
        }
    }
    unsigned short* pl = Pl[wid];
#pragma unroll
    for (int mi = 0; mi < 4; mi++)
#pragma unroll
        for (int ni = 0; ni < 4; ni++)
#pragma unroll
            for (int j = 0; j < 4; j++)
                pl[(mi * 16 + jbase + j) * 72 + ni * 16 + rsel] = f2bf(accS[mi][ni][j] * rs[mi][j]);
    __syncthreads();

    f32x4 accO[4][2];
#pragma unroll
    for (int mi = 0; mi < 4; mi++) { accO[mi][0] = zero4; accO[mi][1] = zero4; }
#pragma unroll
    for (int kk = 0; kk < 2; kk++) {
        short8 pa[4], vb[2];
#pragma unroll
        for (int mi = 0; mi < 4; mi++)
            pa[mi] = *(const short8*)(pl + (mi * 16 + rsel) * 72 + (kk << 5) + ksel);
#pragma unroll
        for (int ni = 0; ni < 2; ni++)
            vb[ni] = *(const short8*)(vt + (ni * 16 + rsel) * 72 + (kk << 5) + ksel);
#pragma unroll
        for (int mi = 0; mi < 4; mi++)
#pragma unroll
            for (int ni = 0; ni < 2; ni++)
                accO[mi][ni] = __builtin_amdgcn_mfma_f32_16x16x32_bf16(pa[mi], vb[ni], accO[mi][ni], 0, 0, 0);
    }
    unsigned short* op = obuf + (size_t)win * 32768 + h * 32;
#pragma unroll
    for (int mi = 0; mi < 4; mi++)
#pragma unroll
        for (int ni = 0; ni < 2; ni++)
#pragma unroll
            for (int j = 0; j < 4; j++)
                op[(size_t)(mi * 16 + jbase + j) * 512 + ni * 16 + rsel] = f2bf(accO[mi][ni][j]);
}

extern "C" void kernel_launch(void* const* d_in, const int* in_sizes, int n_in,
                              void* d_out, int out_size, void* d_ws, size_t ws_size,
                              hipStream_t stream) {
    (void)in_sizes; (void)n_in; (void)out_size; (void)ws_size;
    const float* x       = (const float*)d_in[0];
    const float* norm1_g = (const float*)d_in[1];
    const float* norm1_b = (const float*)d_in[2];
    const float* qkv_w   = (const float*)d_in[3];
    const float* qkv_b   = (const float*)d_in[4];
    const float* rel_b   = (const float*)d_in[5];
    const float* proj_w  = (const float*)d_in[6];
    const float* proj_b  = (const float*)d_in[7];
    const float* norm2_g = (const float*)d_in[8];
    const float* norm2_b = (const float*)d_in[9];
    const float* fc1_w   = (const float*)d_in[10];
    const float* fc1_b   = (const float*)d_in[11];
    const float* fc2_w   = (const float*)d_in[12];
    const float* fc2_b   = (const float*)d_in[13];

    char* ws = (char*)d_ws;
    unsigned short* hn   = (unsigned short*)(ws);                 // 32768x512 bf16, reused: obuf, then h2
    unsigned short* qkvb = (unsigned short*)(ws + 33554432);      // 32768x1536 bf16, reused as g1 (134MB)
    unsigned short* obuf = hn;                                    // alias: hn dead after QKV GEMM
    unsigned short* wq   = (unsigned short*)(ws + 167772160);                 // 1536x512 bf16
    unsigned short* wp   = (unsigned short*)(ws + 167772160 + 1572864);       // 512x512
    unsigned short* w1   = (unsigned short*)(ws + 167772160 + 1572864 + 524288);           // 2048x512
    unsigned short* w2   = (unsigned short*)(ws + 167772160 + 1572864 + 524288 + 2097152); // 512x2048
    float* x1f           = (float*)d_out;                         // x1 fp32 in d_out, overwritten by FC2
    float* outf          = (float*)d_out;

    // 0. weights fp32 -> bf16
    f2bf_kernel<<<768, 256, 0, stream>>>(qkv_w, wq);
    f2bf_kernel<<<256, 256, 0, stream>>>(proj_w, wp);
    f2bf_kernel<<<1024, 256, 0, stream>>>(fc1_w, w1);
    f2bf_kernel<<<1024, 256, 0, stream>>>(fc2_w, w2);
    // 1. h = roll(LN1(x), -32)
    ln_kernel<<<8192, 256, 0, stream>>>(x, norm1_g, norm1_b, hn, SHIFT_);
    // 2. qkv = h @ qkv_w^T + qkv_b   (bf16 out)
    gemm_kernel<1536, 512, 0, false><<<768, 512, 0, stream>>>(hn, wq, qkv_b, qkvb, nullptr, 768);
    // 3. windowed attention (MFMA version; obuf aliases hn)
    attn_kernel<<<2048, 256, 0, stream>>>(qkvb, rel_b, obuf);
    // 4. x1 = x + roll(o @ proj_w^T + proj_b, +32)   (fp32 out -> d_out)
    gemm_kernel<512, 512, 2, true><<<256, 512, 0, stream>>>(obuf, wp, proj_b, x1f, x, 256);
    // 5. h2 = LN2(x1)   (fp32 in, bf16 out)
    ln_kernel<<<8192, 256, 0, stream>>>(x1f, norm2_g, norm2_b, hn, 0);
    // 6. g1 = gelu(h2 @ fc1_w^T + fc1_b)   (bf16 out)
    gemm_kernel<2048, 512, 1, false><<<1024, 512, 0, stream>>>(hn, w1, fc1_b, qkvb, nullptr, 1024);
    // 7. out = x1 + g1 @ fc2_w^T + fc2_b   (fp32 out -> d_out, in-place residual)
    gemm_kernel<512, 2048, 3, true><<<256, 512, 0, stream>>>(qkvb, w2, fc2_b, outf, x1f, 256);
}

// Round 9
// 432.319 us; speedup vs baseline: 1.3069x; 1.3069x over previous
//
#include <hip/hip_runtime.h>
#include <hip/hip_bf16.h>

typedef short short8 __attribute__((ext_vector_type(8)));
typedef short short4v __attribute__((ext_vector_type(4)));
typedef float f32x4 __attribute__((ext_vector_type(4)));

#define SHIFT_ 32

__device__ __forceinline__ float bf2f(unsigned short u) {
    union { unsigned int i; float f; } z; z.i = ((unsigned)u) << 16; return z.f;
}
__device__ __forceinline__ unsigned short f2bf(float f) {
    union { float f; unsigned int i; } z; z.f = f;
    unsigned int x = z.i;
    x += 0x7fffu + ((x >> 16) & 1u);   // round-to-nearest-even
    return (unsigned short)(x >> 16);
}

// ---------------- fp32 -> bf16 weight conversion (once per launch) --------
__global__ __launch_bounds__(256)
void f2bf_kernel(const float* __restrict__ src, unsigned short* __restrict__ dst) {
    int i = (blockIdx.x * 256 + threadIdx.x) * 4;
    f32x4 v = *(const f32x4*)(src + i);
    short4v o;
#pragma unroll
    for (int j = 0; j < 4; j++) o[j] = (short)f2bf(v[j]);
    *(short4v*)(dst + i) = o;
}

// ---------------- LayerNorm (+roll on source index), fp32 in, bf16 out ----
__global__ __launch_bounds__(256)
void ln_kernel(const float* __restrict__ src,
               const float* __restrict__ gam,
               const float* __restrict__ bet,
               unsigned short* __restrict__ dst, int roll) {
    int wid = threadIdx.x >> 6, lane = threadIdx.x & 63;
    int m = (blockIdx.x << 2) + wid;              // output row in [0, 32768)
    int b = m >> 12, s = m & 4095;
    int ms = (b << 12) | ((s + roll) & 4095);     // source row
    const float* p = src + (size_t)ms * 512 + lane * 8;
    f32x4 v0 = *(const f32x4*)p;
    f32x4 v1 = *(const f32x4*)(p + 4);
    float f[8], sum = 0.f, sq = 0.f;
#pragma unroll
    for (int j = 0; j < 4; j++) { f[j] = v0[j]; f[j + 4] = v1[j]; }
#pragma unroll
    for (int j = 0; j < 8; j++) { sum += f[j]; sq += f[j] * f[j]; }
#pragma unroll
    for (int o = 1; o < 64; o <<= 1) { sum += __shfl_xor(sum, o); sq += __shfl_xor(sq, o); }
    float mean = sum * (1.f / 512.f);
    float rstd = rsqrtf(sq * (1.f / 512.f) - mean * mean + 1e-5f);
    const float* gp = gam + lane * 8;
    const float* bp = bet + lane * 8;
    f32x4 g0 = *(const f32x4*)gp, g1 = *(const f32x4*)(gp + 4);
    f32x4 b0 = *(const f32x4*)bp, b1 = *(const f32x4*)(bp + 4);
    short8 ov;
#pragma unroll
    for (int j = 0; j < 4; j++) {
        ov[j]     = (short)f2bf((f[j] - mean) * rstd * g0[j] + b0[j]);
        ov[j + 4] = (short)f2bf((f[j + 4] - mean) * rstd * g1[j] + b1[j]);
    }
    *(short8*)(dst + (size_t)m * 512 + lane * 8) = ov;
}

// ---------------- 128x128 MFMA GEMM, 2-deep counted-vmcnt pipeline --------
// out = A(M x K) @ Wt(N x K)^T + bias
// EPI: 0 = none, 1 = exact GELU, 2 = +roll(+32) residual (extraf = x fp32),
//      3 = +residual (extraf = x1 fp32)
// OUTF32: write float (d_out) vs bf16 (internal ws tensors)
// LDS slot-swizzle: LDS(row, slot) holds global 16B-slot (slot ^ (row&3)),
// applied on BOTH the staging source address and the ds_read address.
template <int N, int K, int EPI, bool OUTF32>
__global__ __launch_bounds__(256, 3)
void gemm_kernel(const unsigned short* __restrict__ A,
                 const unsigned short* __restrict__ Wt,
                 const float* __restrict__ bias,
                 void* __restrict__ outv,
                 const float* __restrict__ extraf, int nwg) {
    __shared__ __attribute__((aligned(16))) unsigned short sA[2][4096];
    __shared__ __attribute__((aligned(16))) unsigned short sB[2][4096];
    // T1: XCD-aware swizzle (grids are multiples of 8; bijective)
    int cpx = nwg >> 3;
    int bid = (blockIdx.x & 7) * cpx + (blockIdx.x >> 3);
    const int nbx = N / 128;
    int bcol = bid % nbx, brow = bid / nbx;
    int m0 = brow << 7, n0 = bcol << 7;
    int t = threadIdx.x, lane = t & 63;
    int wr = (t >> 7) << 6;          // wave row block (0 / 64)
    int wc = ((t >> 6) & 1) << 6;    // wave col block (0 / 64)
    int rsel = lane & 15;
    int slot = (((lane >> 4) ^ (lane & 3)) << 3);   // swizzled 16B slot (ushorts)

    // staging chunks (fixed per thread): c0 = t, c1 = t+256; row = c>>2
    int r0 = t >> 2;
    int s0 = (((t & 3) ^ (r0 & 3)) << 3);           // pre-swizzled source slot
    int r1 = (t + 256) >> 2;
    int s1 = ((((t + 256) & 3) ^ (r1 & 3)) << 3);

#define STAGE(buf, k0)                                                                  \
    do {                                                                                \
        __builtin_amdgcn_global_load_lds(                                               \
            (const __attribute__((address_space(1))) void*)(A + (size_t)(m0 + r0) * K + (k0) + s0), \
            (__attribute__((address_space(3))) void*)(sA[buf] + t * 8), 16, 0, 0);      \
        __builtin_amdgcn_global_load_lds(                                               \
            (const __attribute__((address_space(1))) void*)(Wt + (size_t)(n0 + r0) * K + (k0) + s0), \
            (__attribute__((address_space(3))) void*)(sB[buf] + t * 8), 16, 0, 0);      \
        __builtin_amdgcn_global_load_lds(                                               \
            (const __attribute__((address_space(1))) void*)(A + (size_t)(m0 + r1) * K + (k0) + s1), \
            (__attribute__((address_space(3))) void*)(sA[buf] + (t + 256) * 8), 16, 0, 0); \
        __builtin_amdgcn_global_load_lds(                                               \
            (const __attribute__((address_space(1))) void*)(Wt + (size_t)(n0 + r1) * K + (k0) + s1), \
            (__attribute__((address_space(3))) void*)(sB[buf] + (t + 256) * 8), 16, 0, 0); \
    } while (0)

    f32x4 zero4 = {0.f, 0.f, 0.f, 0.f};
    f32x4 acc[4][4];
#pragma unroll
    for (int mi = 0; mi < 4; mi++)
#pragma unroll
        for (int ni = 0; ni < 4; ni++) acc[mi][ni] = zero4;

    const int NT = K / 32;
    STAGE(0, 0);               // 4 loads: tile 0
    STAGE(1, 32);              // 4 loads: tile 1 (8 outstanding)
    int cur = 0;
    for (int tt = 0; tt < NT; tt++) {
        // wait until THIS tile's 4 loads landed; keep next tile's 4 in flight
        if (tt < NT - 1) asm volatile("s_waitcnt vmcnt(4)" ::: "memory");
        else             asm volatile("s_waitcnt vmcnt(0)" ::: "memory");
        __builtin_amdgcn_sched_barrier(0);
        __builtin_amdgcn_s_barrier();          // all waves' tile-tt loads landed
        __builtin_amdgcn_sched_barrier(0);
        short8 af[4], bf4[4];
#pragma unroll
        for (int mi = 0; mi < 4; mi++)
            af[mi] = *(const short8*)(sA[cur] + (wr + mi * 16 + rsel) * 32 + slot);
#pragma unroll
        for (int ni = 0; ni < 4; ni++)
            bf4[ni] = *(const short8*)(sB[cur] + (wc + ni * 16 + rsel) * 32 + slot);
#pragma unroll
        for (int mi = 0; mi < 4; mi++)
#pragma unroll
            for (int ni = 0; ni < 4; ni++)
                acc[mi][ni] = __builtin_amdgcn_mfma_f32_16x16x32_bf16(af[mi], bf4[ni], acc[mi][ni], 0, 0, 0);
        __builtin_amdgcn_sched_barrier(0);
        __builtin_amdgcn_s_barrier();          // all waves done reading buf[cur]
        __builtin_amdgcn_sched_barrier(0);
        if (tt + 2 < NT) STAGE(cur, (tt + 2) * 32);   // refill freed buffer
        cur ^= 1;
    }
#undef STAGE

    // epilogue: C/D layout col = lane&15, row = (lane>>4)*4 + j  [m89/m91]
    int jbase = (lane >> 4) << 2;
#pragma unroll
    for (int ni = 0; ni < 4; ni++) {
        int gcol = n0 + wc + ni * 16 + rsel;
        float bv = bias[gcol];
#pragma unroll
        for (int mi = 0; mi < 4; mi++) {
#pragma unroll
            for (int j = 0; j < 4; j++) {
                int grow = m0 + wr + mi * 16 + jbase + j;
                float v = acc[mi][ni][j] + bv;
                size_t oidx;
                if (EPI == 2) {
                    int orow = (grow & ~4095) | ((grow + SHIFT_) & 4095);  // roll +32 within batch
                    oidx = (size_t)orow * N + gcol;
                    v += extraf[oidx];
                } else {
                    oidx = (size_t)grow * N + gcol;
                    if (EPI == 1) v = 0.5f * v * (1.f + erff(v * 0.70710678118654752f));
                    if (EPI == 3) v += extraf[oidx];
                }
                if (OUTF32) ((float*)outv)[oidx] = v;
                else        ((unsigned short*)outv)[oidx] = f2bf(v);
            }
        }
    }
}

// ---------------- MFMA window attention: one wave per (window, head) ------
__global__ __launch_bounds__(256, 2)
void attn_kernel(const unsigned short* __restrict__ qkv,
                 const float* __restrict__ relb,
                 unsigned short* __restrict__ obuf) {
    __shared__ __attribute__((aligned(16))) unsigned short Pl[4][64 * 72];
    __shared__ __attribute__((aligned(16))) unsigned short Vt[4][32 * 72];
    __shared__ float biasd[4][128];
    int wid = threadIdx.x >> 6, lane = threadIdx.x & 63;
    int task = (blockIdx.x << 2) + wid;   // 8192 tasks = 512 windows x 16 heads
    int win = task >> 4, h = task & 15;
    const unsigned short* base = qkv + (size_t)win * 98304 + h * 32;

    float* bd = biasd[wid];
    bd[lane] = relb[lane * 16 + h];
    if (lane < 63) bd[lane + 64] = relb[(lane + 64) * 16 + h];

    int rsel = lane & 15, ksel = (lane >> 4) << 3;
    short8 qf[4], kf[4];
#pragma unroll
    for (int i = 0; i < 4; i++) {
        qf[i] = *(const short8*)(base + (size_t)(i * 16 + rsel) * 1536 + ksel);
        kf[i] = *(const short8*)(base + (size_t)(i * 16 + rsel) * 1536 + 512 + ksel);
    }
    f32x4 zero4 = {0.f, 0.f, 0.f, 0.f};
    f32x4 accS[4][4];
#pragma unroll
    for (int mi = 0; mi < 4; mi++)
#pragma unroll
        for (int ni = 0; ni < 4; ni++) accS[mi][ni] = zero4;
#pragma unroll
    for (int mi = 0; mi < 4; mi++)
#pragma unroll
        for (int ni = 0; ni < 4; ni++)
            accS[mi][ni] = __builtin_amdgcn_mfma_f32_16x16x32_bf16(qf[mi], kf[ni], accS[mi][ni], 0, 0, 0);

    // stage V^T into LDS: vt[d][k] = v[k][d], padded stride 72
    unsigned short* vt = Vt[wid];
#pragma unroll 8
    for (int it = 0; it < 32; it++) {
        int idx = (it << 6) + lane;
        int vr = idx >> 5, vd = idx & 31;
        vt[vd * 72 + vr] = base[(size_t)vr * 1536 + 1024 + vd];
    }
    __syncthreads();

    const float scale = 0.17677669529663687f;  // 1/sqrt(32)
    bool masked = ((win & 63) == 63);
    int jbase = (lane >> 4) << 2;
    float rs[4][4];
#pragma unroll
    for (int mi = 0; mi < 4; mi++) {
#pragma unroll
        for (int ni = 0; ni < 4; ni++) {
            int colb = ni * 16 + rsel;
#pragma unroll
            for (int j = 0; j < 4; j++) {
                int row = mi * 16 + jbase + j;
                float v = accS[mi][ni][j] * scale + bd[row - colb + 63];
                if (masked && ((row < 32) != (colb < 32))) v -= 100.f;
                accS[mi][ni][j] = v;
            }
        }
#pragma unroll
        for (int j = 0; j < 4; j++) {
            float m = fmaxf(fmaxf(accS[mi][0][j], accS[mi][1][j]),
                            fmaxf(accS[mi][2][j], accS[mi][3][j]));
            m = fmaxf(m, __shfl_xor(m, 1));
            m = fmaxf(m, __shfl_xor(m, 2));
            m = fmaxf(m, __shfl_xor(m, 4));
            m = fmaxf(m, __shfl_xor(m, 8));
            float ssum = 0.f;
#pragma unroll
            for (int ni = 0; ni < 4; ni++) {
                float p = __expf(accS[mi][ni][j] - m);
                accS[mi][ni][j] = p; ssum += p;
            }
            ssum += __shfl_xor(ssum, 1);
            ssum += __shfl_xor(ssum, 2);
            ssum += __shfl_xor(ssum, 4);
            ssum += __shfl_xor(ssum, 8);
            rs[mi][j] = 1.f / ssum;
        }
    }
    unsigned short* pl = Pl[wid];
#pragma unroll
    for (int mi = 0; mi < 4; mi++)
#pragma unroll
        for (int ni = 0; ni < 4; ni++)
#pragma unroll
            for (int j = 0; j < 4; j++)
                pl[(mi * 16 + jbase + j) * 72 + ni * 16 + rsel] = f2bf(accS[mi][ni][j] * rs[mi][j]);
    __syncthreads();

    f32x4 accO[4][2];
#pragma unroll
    for (int mi = 0; mi < 4; mi++) { accO[mi][0] = zero4; accO[mi][1] = zero4; }
#pragma unroll
    for (int kk = 0; kk < 2; kk++) {
        short8 pa[4], vb[2];
#pragma unroll
        for (int mi = 0; mi < 4; mi++)
            pa[mi] = *(const short8*)(pl + (mi * 16 + rsel) * 72 + (kk << 5) + ksel);
#pragma unroll
        for (int ni = 0; ni < 2; ni++)
            vb[ni] = *(const short8*)(vt + (ni * 16 + rsel) * 72 + (kk << 5) + ksel);
#pragma unroll
        for (int mi = 0; mi < 4; mi++)
#pragma unroll
            for (int ni = 0; ni < 2; ni++)
                accO[mi][ni] = __builtin_amdgcn_mfma_f32_16x16x32_bf16(pa[mi], vb[ni], accO[mi][ni], 0, 0, 0);
    }
    unsigned short* op = obuf + (size_t)win * 32768 + h * 32;
#pragma unroll
    for (int mi = 0; mi < 4; mi++)
#pragma unroll
        for (int ni = 0; ni < 2; ni++)
#pragma unroll
            for (int j = 0; j < 4; j++)
                op[(size_t)(mi * 16 + jbase + j) * 512 + ni * 16 + rsel] = f2bf(accO[mi][ni][j]);
}

extern "C" void kernel_launch(void* const* d_in, const int* in_sizes, int n_in,
                              void* d_out, int out_size, void* d_ws, size_t ws_size,
                              hipStream_t stream) {
    (void)in_sizes; (void)n_in; (void)out_size; (void)ws_size;
    const float* x       = (const float*)d_in[0];
    const float* norm1_g = (const float*)d_in[1];
    const float* norm1_b = (const float*)d_in[2];
    const float* qkv_w   = (const float*)d_in[3];
    const float* qkv_b   = (const float*)d_in[4];
    const float* rel_b   = (const float*)d_in[5];
    const float* proj_w  = (const float*)d_in[6];
    const float* proj_b  = (const float*)d_in[7];
    const float* norm2_g = (const float*)d_in[8];
    const float* norm2_b = (const float*)d_in[9];
    const float* fc1_w   = (const float*)d_in[10];
    const float* fc1_b   = (const float*)d_in[11];
    const float* fc2_w   = (const float*)d_in[12];
    const float* fc2_b   = (const float*)d_in[13];

    char* ws = (char*)d_ws;
    unsigned short* hn   = (unsigned short*)(ws);                 // 32768x512 bf16, reused: obuf, then h2
    unsigned short* qkvb = (unsigned short*)(ws + 33554432);      // 32768x1536 bf16, reused as g1 (134MB)
    unsigned short* obuf = hn;                                    // alias: hn dead after QKV GEMM
    unsigned short* wq   = (unsigned short*)(ws + 167772160);                 // 1536x512 bf16
    unsigned short* wp   = (unsigned short*)(ws + 167772160 + 1572864);       // 512x512
    unsigned short* w1   = (unsigned short*)(ws + 167772160 + 1572864 + 524288);           // 2048x512
    unsigned short* w2   = (unsigned short*)(ws + 167772160 + 1572864 + 524288 + 2097152); // 512x2048
    float* x1f           = (float*)d_out;                         // x1 fp32 in d_out, overwritten by FC2
    float* outf          = (float*)d_out;

    // 0. weights fp32 -> bf16
    f2bf_kernel<<<768, 256, 0, stream>>>(qkv_w, wq);
    f2bf_kernel<<<256, 256, 0, stream>>>(proj_w, wp);
    f2bf_kernel<<<1024, 256, 0, stream>>>(fc1_w, w1);
    f2bf_kernel<<<1024, 256, 0, stream>>>(fc2_w, w2);
    // 1. h = roll(LN1(x), -32)
    ln_kernel<<<8192, 256, 0, stream>>>(x, norm1_g, norm1_b, hn, SHIFT_);
    // 2. qkv = h @ qkv_w^T + qkv_b   (bf16 out)
    gemm_kernel<1536, 512, 0, false><<<3072, 256, 0, stream>>>(hn, wq, qkv_b, qkvb, nullptr, 3072);
    // 3. windowed attention (MFMA version; obuf aliases hn)
    attn_kernel<<<2048, 256, 0, stream>>>(qkvb, rel_b, obuf);
    // 4. x1 = x + roll(o @ proj_w^T + proj_b, +32)   (fp32 out -> d_out)
    gemm_kernel<512, 512, 2, true><<<1024, 256, 0, stream>>>(obuf, wp, proj_b, x1f, x, 1024);
    // 5. h2 = LN2(x1)   (fp32 in, bf16 out)
    ln_kernel<<<8192, 256, 0, stream>>>(x1f, norm2_g, norm2_b, hn, 0);
    // 6. g1 = gelu(h2 @ fc1_w^T + fc1_b)   (bf16 out)
    gemm_kernel<2048, 512, 1, false><<<4096, 256, 0, stream>>>(hn, w1, fc1_b, qkvb, nullptr, 4096);
    // 7. out = x1 + g1 @ fc2_w^T + fc2_b   (fp32 out -> d_out, in-place residual)
    gemm_kernel<512, 2048, 3, true><<<1024, 256, 0, stream>>>(qkvb, w2, fc2_b, outf, x1f, 1024);
}